// Round 1
// baseline (437.220 us; speedup 1.0000x reference)
//
#include <hip/hip_runtime.h>
#include <hip/hip_bf16.h>

// out = (x + 5) * 2 - 1 = 2*x + 9, elementwise over 8192x8192 fp32.
// Memory-bound streaming kernel: float4 loads/stores, grid-stride loop.

__global__ void __launch_bounds__(256) fma_elementwise_f32x4(
    const float4* __restrict__ in, float4* __restrict__ out, int n4) {
    int idx = blockIdx.x * blockDim.x + threadIdx.x;
    int stride = gridDim.x * blockDim.x;
    for (int i = idx; i < n4; i += stride) {
        float4 v = in[i];
        float4 r;
        r.x = fmaf(v.x, 2.0f, 9.0f);
        r.y = fmaf(v.y, 2.0f, 9.0f);
        r.z = fmaf(v.z, 2.0f, 9.0f);
        r.w = fmaf(v.w, 2.0f, 9.0f);
        out[i] = r;
    }
}

// Tail handler for n not divisible by 4 (not needed for 8192^2, but cheap).
__global__ void fma_elementwise_f32_tail(
    const float* __restrict__ in, float* __restrict__ out, int start, int n) {
    int i = start + blockIdx.x * blockDim.x + threadIdx.x;
    if (i < n) out[i] = fmaf(in[i], 2.0f, 9.0f);
}

extern "C" void kernel_launch(void* const* d_in, const int* in_sizes, int n_in,
                              void* d_out, int out_size, void* d_ws, size_t ws_size,
                              hipStream_t stream) {
    const float* x = (const float*)d_in[0];
    float* out = (float*)d_out;
    int n = in_sizes[0];
    int n4 = n / 4;

    const int block = 256;
    // Memory-bound: cap grid at ~8 blocks/CU * 256 CUs, grid-stride the rest.
    int grid = (n4 + block - 1) / block;
    if (grid > 2048) grid = 2048;
    if (grid < 1) grid = 1;

    fma_elementwise_f32x4<<<grid, block, 0, stream>>>(
        (const float4*)x, (float4*)out, n4);

    int tail_start = n4 * 4;
    int tail = n - tail_start;
    if (tail > 0) {
        fma_elementwise_f32_tail<<<1, 64, 0, stream>>>(x, out, tail_start, n);
    }
}